// Round 6
// baseline (166372.876 us; speedup 1.0000x reference)
//
#include <hip/hip_runtime.h>
#include <math.h>

#pragma clang fp contract(fast)

typedef float v2f __attribute__((ext_vector_type(2)));
typedef float v4f __attribute__((ext_vector_type(4)));

#define EPSV 1e-5f
// ALU|VALU|SALU may cross (hide trans latency); VMEM/DS pinned (no re-hoist -> no spill)
#define SBARF() __builtin_amdgcn_sched_barrier(0x7)

struct __align__(16) WS {
  float W1[128]; float b1[32]; float W2[128]; float b2[4];
  float G1[128]; float gb1[32]; float l1g[32]; float l1b[32];
  float G2[1024]; float gb2[32]; float l2g[32]; float l2b[32];
  float G3[128]; float gb3[4];
};

__device__ __forceinline__ v2f vlo(v4f v) { return __builtin_shufflevector(v, v, 0, 1); }
__device__ __forceinline__ v2f vhi(v4f v) { return __builtin_shufflevector(v, v, 2, 3); }

// a += s * w  -> v_pk_fma_f32 (scalar s broadcasts via op_sel)
__device__ __forceinline__ v2f pf(float s, v2f w, v2f a) { return a + s * w; }

__device__ __forceinline__ float ftanh(float x) {
  // tanh(x) = 1 - 2/(exp(2x)+1); clamp to avoid inf
  x = fminf(15.0f, fmaxf(-15.0f, x));
  float e = __expf(x + x);
  float r = __builtin_amdgcn_rcpf(e + 1.0f);
  return fmaf(-2.0f, r, 1.0f);
}

// LayerNorm over 32 values held as 8 v2f per lane across a lane pair.
// g/b pre-offset to this lane's 16 rows (as v2f).
__device__ __forceinline__ void lnorm8v(v2f* t, const v2f* g, const v2f* b) {
  v2f sv = {0.f, 0.f}, ssv = {0.f, 0.f};
  #pragma unroll
  for (int i = 0; i < 8; ++i) { sv += t[i]; ssv += t[i] * t[i]; }
  float s = sv.x + sv.y, ss = ssv.x + ssv.y;
  s  += __shfl_xor(s, 1);
  ss += __shfl_xor(ss, 1);
  float m = s * 0.03125f;
  float v = fmaf(-m, m, ss * 0.03125f);
  float r = __frsqrt_rn(v + EPSV);
  #pragma unroll
  for (int i = 0; i < 8; ++i) t[i] = ((t[i] - m) * r) * g[i] + b[i];
}

// f-eval split across a lane pair; packed-fp32 (v2f) matmul accumulators.
__device__ __forceinline__ void fode(const WS* w, int p, bool pb,
                                     const float y[4], float out[4]) {
  const v4f* W1v  = (const v4f*)w->W1;
  const v4f* b1v  = (const v4f*)w->b1;
  const v4f* W2v  = (const v4f*)w->W2;
  const v4f* G1v  = (const v4f*)w->G1;
  const v4f* gb1v = (const v4f*)w->gb1;
  const v4f* G2v  = (const v4f*)w->G2;
  const v4f* gb2v = (const v4f*)w->gb2;
  const v4f* G3v  = (const v4f*)w->G3;
  const int j0 = p * 4;    // my float4 column-group base (of 8)
  const int r0 = p * 16;   // my row base (of 32)

  // ---- magnitude net: partial over my 16 hidden units ----
  v2f mlo = {0.f, 0.f}, mhi = {0.f, 0.f};
  #pragma unroll
  for (int j = 0; j < 4; ++j) {
    v4f bb = b1v[j0 + j];
    v2f alo = vlo(bb), ahi = vhi(bb);
    #pragma unroll
    for (int i = 0; i < 4; ++i) {
      v4f wv = W1v[i * 8 + j0 + j];
      alo = pf(y[i], vlo(wv), alo);
      ahi = pf(y[i], vhi(wv), ahi);
    }
    float h0 = ftanh(alo.x), h1 = ftanh(alo.y);
    float h2 = ftanh(ahi.x), h3 = ftanh(ahi.y);
    v4f w0 = W2v[r0 + 4*j + 0]; mlo = pf(h0, vlo(w0), mlo); mhi = pf(h0, vhi(w0), mhi);
    v4f w1 = W2v[r0 + 4*j + 1]; mlo = pf(h1, vlo(w1), mlo); mhi = pf(h1, vhi(w1), mhi);
    v4f w2 = W2v[r0 + 4*j + 2]; mlo = pf(h2, vlo(w2), mlo); mhi = pf(h2, vhi(w2), mhi);
    v4f w3 = W2v[r0 + 4*j + 3]; mlo = pf(h3, vlo(w3), mlo); mhi = pf(h3, vhi(w3), mhi);
    SBARF();
  }

  // ---- gating layer 1: my 16 of t = LN(tanh(y@G1+gb1)) ----
  v2f tm[8];
  #pragma unroll
  for (int j = 0; j < 4; ++j) {
    v4f bb = gb1v[j0 + j];
    v2f alo = vlo(bb), ahi = vhi(bb);
    #pragma unroll
    for (int i = 0; i < 4; ++i) {
      v4f wv = G1v[i * 8 + j0 + j];
      alo = pf(y[i], vlo(wv), alo);
      ahi = pf(y[i], vhi(wv), ahi);
    }
    tm[2*j]   = v2f{ftanh(alo.x), ftanh(alo.y)};
    tm[2*j+1] = v2f{ftanh(ahi.x), ftanh(ahi.y)};
    SBARF();
  }
  lnorm8v(tm, (const v2f*)(w->l1g + r0), (const v2f*)(w->l1b + r0));

  // ---- exchange: build full 32-vector of multipliers (static idx only) ----
  float tf[32];
  #pragma unroll
  for (int i = 0; i < 8; ++i) {
    float a0 = tm[i].x, a1 = tm[i].y;
    float o0 = __shfl_xor(a0, 1), o1 = __shfl_xor(a1, 1);
    tf[2*i]      = pb ? o0 : a0;
    tf[2*i+1]    = pb ? o1 : a1;
    tf[16+2*i]   = pb ? a0 : o0;
    tf[16+2*i+1] = pb ? a1 : o1;
  }
  SBARF();

  // ---- gating layer 2: my 16 of u = LN(tanh(t@G2+gb2)) ----
  v2f um[8];
  #pragma unroll
  for (int j = 0; j < 4; ++j) {
    v4f bb = gb2v[j0 + j];
    v2f alo = vlo(bb), ahi = vhi(bb);
    #pragma unroll
    for (int i = 0; i < 32; ++i) {
      v4f wv = G2v[i * 8 + j0 + j];
      alo = pf(tf[i], vlo(wv), alo);
      ahi = pf(tf[i], vhi(wv), ahi);
      if (i == 15) SBARF();
    }
    um[2*j]   = v2f{ftanh(alo.x), ftanh(alo.y)};
    um[2*j+1] = v2f{ftanh(ahi.x), ftanh(ahi.y)};
    SBARF();
  }
  lnorm8v(um, (const v2f*)(w->l2g + r0), (const v2f*)(w->l2b + r0));

  // ---- G3 partial over my 16 rows, then pair-reduce ----
  v2f zlo = {0.f, 0.f}, zhi = {0.f, 0.f};
  #pragma unroll
  for (int i = 0; i < 16; ++i) {
    float s = (i & 1) ? um[i >> 1].y : um[i >> 1].x;
    v4f wv = G3v[r0 + i];
    zlo = pf(s, vlo(wv), zlo);
    zhi = pf(s, vhi(wv), zhi);
    if (i == 7) SBARF();
  }
  SBARF();

  v4f b2v  = *(const v4f*)w->b2;
  v4f gb3v = *(const v4f*)w->gb3;
  float zx = zlo.x + __shfl_xor(zlo.x, 1) + gb3v.x;
  float zy = zlo.y + __shfl_xor(zlo.y, 1) + gb3v.y;
  float zz = zhi.x + __shfl_xor(zhi.x, 1) + gb3v.z;
  float zw = zhi.y + __shfl_xor(zhi.y, 1) + gb3v.w;
  float mx = mlo.x + __shfl_xor(mlo.x, 1) + b2v.x;
  float my = mlo.y + __shfl_xor(mlo.y, 1) + b2v.y;
  float mz = mhi.x + __shfl_xor(mhi.x, 1) + b2v.z;
  float mw = mhi.y + __shfl_xor(mhi.y, 1) + b2v.w;
  out[0] = mx * __expf(-zx * zx);
  out[1] = my * __expf(-zy * zy);
  out[2] = mz * __expf(-zz * zz);
  out[3] = mw * __expf(-zw * zw);
}

__global__ __launch_bounds__(256, 2) void ode_kernel(
    const float* __restrict__ s_grid, const float* __restrict__ y0,
    const float* __restrict__ W1, const float* __restrict__ b1,
    const float* __restrict__ W2, const float* __restrict__ b2,
    const float* __restrict__ G1, const float* __restrict__ gb1,
    const float* __restrict__ l1g, const float* __restrict__ l1b,
    const float* __restrict__ G2, const float* __restrict__ gb2,
    const float* __restrict__ l2g, const float* __restrict__ l2b,
    const float* __restrict__ G3, const float* __restrict__ gb3,
    float* __restrict__ out, int T, int B) {
  __shared__ WS w;
  __shared__ float sg[512];
  const int tx = threadIdx.x;

  for (int i = tx; i < 128; i += 256) {
    w.W1[i] = W1[i]; w.W2[i] = W2[i]; w.G1[i] = G1[i]; w.G3[i] = G3[i];
  }
  for (int i = tx; i < 1024; i += 256) w.G2[i] = G2[i];
  if (tx < 32) {
    w.b1[tx] = b1[tx]; w.gb1[tx] = gb1[tx];
    w.l1g[tx] = l1g[tx]; w.l1b[tx] = l1b[tx];
    w.gb2[tx] = gb2[tx];
    w.l2g[tx] = l2g[tx]; w.l2b[tx] = l2b[tx];
  }
  if (tx < 4) { w.b2[tx] = b2[tx]; w.gb3[tx] = gb3[tx]; }
  for (int i = tx; i < T && i < 512; i += 256) sg[i] = s_grid[i];
  __syncthreads();

  const int tid = blockIdx.x * 256 + tx;
  const int sys = tid >> 1;        // system index (2 lanes per system)
  const int p   = tid & 1;         // which half of the hidden layers
  const bool pb = (p != 0);
  if (sys >= B) return;

  float4 y0v = ((const float4*)y0)[sys];
  float y[4] = {y0v.x, y0v.y, y0v.z, y0v.w};
  if (!pb) ((float4*)out)[sys] = y0v;  // t = 0 row

  #pragma unroll 1
  for (int t = 0; t < T - 1; ++t) {
    const float h = sg[t + 1] - sg[t];
    float k[4], ksum[4], yt[4];

    fode(&w, p, pb, y, k);
    #pragma unroll
    for (int c = 0; c < 4; ++c) { ksum[c] = k[c]; yt[c] = fmaf(0.5f * h, k[c], y[c]); }
    SBARF();
    fode(&w, p, pb, yt, k);
    #pragma unroll
    for (int c = 0; c < 4; ++c) { ksum[c] = fmaf(2.0f, k[c], ksum[c]); yt[c] = fmaf(0.5f * h, k[c], y[c]); }
    SBARF();
    fode(&w, p, pb, yt, k);
    #pragma unroll
    for (int c = 0; c < 4; ++c) { ksum[c] = fmaf(2.0f, k[c], ksum[c]); yt[c] = fmaf(h, k[c], y[c]); }
    SBARF();
    fode(&w, p, pb, yt, k);
    #pragma unroll
    for (int c = 0; c < 4; ++c)
      y[c] = fmaf(h * (1.0f / 6.0f), ksum[c] + k[c], y[c]);

    if (!pb) {
      float4 yo; yo.x = y[0]; yo.y = y[1]; yo.z = y[2]; yo.w = y[3];
      ((float4*)out)[(size_t)(t + 1) * B + sys] = yo;
    }
  }
}

extern "C" void kernel_launch(void* const* d_in, const int* in_sizes, int n_in,
                              void* d_out, int out_size, void* d_ws, size_t ws_size,
                              hipStream_t stream) {
  const float* s_grid = (const float*)d_in[0];
  const float* y0     = (const float*)d_in[1];
  const float* W1     = (const float*)d_in[2];
  const float* b1     = (const float*)d_in[3];
  const float* W2     = (const float*)d_in[4];
  const float* b2     = (const float*)d_in[5];
  const float* G1     = (const float*)d_in[6];
  const float* gb1    = (const float*)d_in[7];
  const float* l1g    = (const float*)d_in[8];
  const float* l1b    = (const float*)d_in[9];
  const float* G2     = (const float*)d_in[10];
  const float* gb2    = (const float*)d_in[11];
  const float* l2g    = (const float*)d_in[12];
  const float* l2b    = (const float*)d_in[13];
  const float* G3     = (const float*)d_in[14];
  const float* gb3    = (const float*)d_in[15];

  const int T = in_sizes[0];
  const int B = in_sizes[1] / 4;

  const int threads = 2 * B;  // two lanes per system
  dim3 block(256);
  dim3 grid((threads + 255) / 256);
  hipLaunchKernelGGL(ode_kernel, grid, block, 0, stream,
                     s_grid, y0, W1, b1, W2, b2, G1, gb1, l1g, l1b,
                     G2, gb2, l2g, l2b, G3, gb3, (float*)d_out, T, B);
}

// Round 7
// 5938.067 us; speedup vs baseline: 28.0180x; 28.0180x over previous
//
#include <hip/hip_runtime.h>
#include <math.h>

typedef float v2f __attribute__((ext_vector_type(2)));

#define EPSV 1e-5f
#define SBAR() __builtin_amdgcn_sched_barrier(0)

struct __align__(16) WS {
  float W1[128]; float b1[32]; float W2[128]; float b2[4];
  float G1[128]; float gb1[32]; float l1g[32]; float l1b[32];
  float G2[1024]; float gb2[32]; float l2g[32]; float l2b[32];
  float G3[128]; float gb3[4];
};

// packed a += s * {wx,wy}  -> v_pk_fma_f32. v2f ONLY as named locals
// (ext_vector ARRAYS / pointers go to scratch -- R6 lesson).
__device__ __forceinline__ v2f pkfma(float s, float wx, float wy, v2f a) {
  v2f w = {wx, wy};
  v2f sv = {s, s};
  return __builtin_elementwise_fma(sv, w, a);
}

__device__ __forceinline__ float ftanh(float x) {
  // tanh(x) = 1 - 2/(exp(2x)+1); clamp to avoid inf
  x = fminf(15.0f, fmaxf(-15.0f, x));
  float e = __expf(x + x);
  float r = __builtin_amdgcn_rcpf(e + 1.0f);
  return fmaf(-2.0f, r, 1.0f);
}

// LayerNorm over 32 values held 16-per-lane across a lane pair.
// g/b pointers pre-offset to this lane's 16 rows. Scalar float path (R5).
__device__ __forceinline__ void lnorm16_pair(float* t, const float* g, const float* b) {
  float s = 0.f, ss = 0.f;
  #pragma unroll
  for (int i = 0; i < 16; ++i) { s += t[i]; ss = fmaf(t[i], t[i], ss); }
  s  += __shfl_xor(s, 1);
  ss += __shfl_xor(ss, 1);
  float m = s * 0.03125f;
  float v = fmaf(-m, m, ss * 0.03125f);
  float r = __frsqrt_rn(v + EPSV);
  #pragma unroll
  for (int i = 0; i < 16; ++i) t[i] = fmaf((t[i] - m) * r, g[i], b[i]);
}

// f-eval split across a lane pair: lane p in {0,1} owns output columns
// [16p, 16p+16). Matmul accumulators packed (v_pk_fma_f32) as named v2f.
__device__ __forceinline__ void fode(const WS* w, int p, bool pb,
                                     const float y[4], float out[4]) {
  const float4* W1v  = (const float4*)w->W1;
  const float4* b1v  = (const float4*)w->b1;
  const float4* W2v  = (const float4*)w->W2;
  const float4* G1v  = (const float4*)w->G1;
  const float4* gb1v = (const float4*)w->gb1;
  const float4* G2v  = (const float4*)w->G2;
  const float4* gb2v = (const float4*)w->gb2;
  const float4* G3v  = (const float4*)w->G3;
  const int j0 = p * 4;    // my float4 column-group base (of 8)
  const int r0 = p * 16;   // my row base (of 32)

  // ---- magnitude net: partial over my 16 hidden units ----
  v2f mlo = {0.f, 0.f}, mhi = {0.f, 0.f};
  #pragma unroll
  for (int j = 0; j < 4; ++j) {
    float4 bb = b1v[j0 + j];
    v2f alo = {bb.x, bb.y};
    v2f ahi = {bb.z, bb.w};
    #pragma unroll
    for (int i = 0; i < 4; ++i) {
      float4 wv = W1v[i * 8 + j0 + j];
      alo = pkfma(y[i], wv.x, wv.y, alo);
      ahi = pkfma(y[i], wv.z, wv.w, ahi);
    }
    float h0 = ftanh(alo.x), h1 = ftanh(alo.y);
    float h2 = ftanh(ahi.x), h3 = ftanh(ahi.y);
    float4 w0 = W2v[r0 + 4*j + 0];
    mlo = pkfma(h0, w0.x, w0.y, mlo); mhi = pkfma(h0, w0.z, w0.w, mhi);
    float4 w1 = W2v[r0 + 4*j + 1];
    mlo = pkfma(h1, w1.x, w1.y, mlo); mhi = pkfma(h1, w1.z, w1.w, mhi);
    float4 w2 = W2v[r0 + 4*j + 2];
    mlo = pkfma(h2, w2.x, w2.y, mlo); mhi = pkfma(h2, w2.z, w2.w, mhi);
    float4 w3 = W2v[r0 + 4*j + 3];
    mlo = pkfma(h3, w3.x, w3.y, mlo); mhi = pkfma(h3, w3.z, w3.w, mhi);
    SBAR();
  }

  // ---- gating layer 1: my 16 of t = LN(tanh(y@G1+gb1)) ----
  float tm[16];
  #pragma unroll
  for (int j = 0; j < 4; ++j) {
    float4 bb = gb1v[j0 + j];
    v2f alo = {bb.x, bb.y};
    v2f ahi = {bb.z, bb.w};
    #pragma unroll
    for (int i = 0; i < 4; ++i) {
      float4 wv = G1v[i * 8 + j0 + j];
      alo = pkfma(y[i], wv.x, wv.y, alo);
      ahi = pkfma(y[i], wv.z, wv.w, ahi);
    }
    tm[4*j+0] = ftanh(alo.x); tm[4*j+1] = ftanh(alo.y);
    tm[4*j+2] = ftanh(ahi.x); tm[4*j+3] = ftanh(ahi.y);
    SBAR();
  }
  lnorm16_pair(tm, w->l1g + r0, w->l1b + r0);

  // ---- exchange: build full 32-vector (static indexing only) ----
  float tf[32];
  #pragma unroll
  for (int i = 0; i < 16; ++i) {
    float o = __shfl_xor(tm[i], 1);
    tf[i]      = pb ? o     : tm[i];
    tf[16 + i] = pb ? tm[i] : o;
  }
  SBAR();

  // ---- gating layer 2: my 16 of u = LN(tanh(t@G2+gb2)) ----
  float um[16];
  #pragma unroll
  for (int j = 0; j < 4; ++j) {
    float4 bb = gb2v[j0 + j];
    v2f alo = {bb.x, bb.y};
    v2f ahi = {bb.z, bb.w};
    #pragma unroll
    for (int i = 0; i < 32; ++i) {
      float4 wv = G2v[i * 8 + j0 + j];
      alo = pkfma(tf[i], wv.x, wv.y, alo);
      ahi = pkfma(tf[i], wv.z, wv.w, ahi);
      if (i == 15) SBAR();
    }
    um[4*j+0] = ftanh(alo.x); um[4*j+1] = ftanh(alo.y);
    um[4*j+2] = ftanh(ahi.x); um[4*j+3] = ftanh(ahi.y);
    SBAR();
  }
  lnorm16_pair(um, w->l2g + r0, w->l2b + r0);

  // ---- G3 partial over my 16 rows, then pair-reduce ----
  v2f zlo = {0.f, 0.f}, zhi = {0.f, 0.f};
  #pragma unroll
  for (int i = 0; i < 16; ++i) {
    float4 wv = G3v[r0 + i];
    zlo = pkfma(um[i], wv.x, wv.y, zlo);
    zhi = pkfma(um[i], wv.z, wv.w, zhi);
    if (i == 7) SBAR();
  }
  SBAR();

  float4 b2v  = *(const float4*)w->b2;
  float4 gb3v = *(const float4*)w->gb3;
  float zx = zlo.x + __shfl_xor(zlo.x, 1) + gb3v.x;
  float zy = zlo.y + __shfl_xor(zlo.y, 1) + gb3v.y;
  float zz = zhi.x + __shfl_xor(zhi.x, 1) + gb3v.z;
  float zw = zhi.y + __shfl_xor(zhi.y, 1) + gb3v.w;
  float mx = mlo.x + __shfl_xor(mlo.x, 1) + b2v.x;
  float my = mlo.y + __shfl_xor(mlo.y, 1) + b2v.y;
  float mz = mhi.x + __shfl_xor(mhi.x, 1) + b2v.z;
  float mw = mhi.y + __shfl_xor(mhi.y, 1) + b2v.w;
  out[0] = mx * __expf(-zx * zx);
  out[1] = my * __expf(-zy * zy);
  out[2] = mz * __expf(-zz * zz);
  out[3] = mw * __expf(-zw * zw);
}

__global__ __launch_bounds__(256, 2) void ode_kernel(
    const float* __restrict__ s_grid, const float* __restrict__ y0,
    const float* __restrict__ W1, const float* __restrict__ b1,
    const float* __restrict__ W2, const float* __restrict__ b2,
    const float* __restrict__ G1, const float* __restrict__ gb1,
    const float* __restrict__ l1g, const float* __restrict__ l1b,
    const float* __restrict__ G2, const float* __restrict__ gb2,
    const float* __restrict__ l2g, const float* __restrict__ l2b,
    const float* __restrict__ G3, const float* __restrict__ gb3,
    float* __restrict__ out, int T, int B) {
  __shared__ WS w;
  __shared__ float sg[512];
  const int tx = threadIdx.x;

  for (int i = tx; i < 128; i += 256) {
    w.W1[i] = W1[i]; w.W2[i] = W2[i]; w.G1[i] = G1[i]; w.G3[i] = G3[i];
  }
  for (int i = tx; i < 1024; i += 256) w.G2[i] = G2[i];
  if (tx < 32) {
    w.b1[tx] = b1[tx]; w.gb1[tx] = gb1[tx];
    w.l1g[tx] = l1g[tx]; w.l1b[tx] = l1b[tx];
    w.gb2[tx] = gb2[tx];
    w.l2g[tx] = l2g[tx]; w.l2b[tx] = l2b[tx];
  }
  if (tx < 4) { w.b2[tx] = b2[tx]; w.gb3[tx] = gb3[tx]; }
  for (int i = tx; i < T && i < 512; i += 256) sg[i] = s_grid[i];
  __syncthreads();

  const int tid = blockIdx.x * 256 + tx;
  const int sys = tid >> 1;        // system index (2 lanes per system)
  const int p   = tid & 1;         // which half of the hidden layers
  const bool pb = (p != 0);
  if (sys >= B) return;

  float4 y0v = ((const float4*)y0)[sys];
  float y[4] = {y0v.x, y0v.y, y0v.z, y0v.w};
  if (!pb) ((float4*)out)[sys] = y0v;  // t = 0 row

  #pragma unroll 1
  for (int t = 0; t < T - 1; ++t) {
    const float h = sg[t + 1] - sg[t];
    float k[4], ksum[4], yt[4];

    fode(&w, p, pb, y, k);
    #pragma unroll
    for (int c = 0; c < 4; ++c) { ksum[c] = k[c]; yt[c] = fmaf(0.5f * h, k[c], y[c]); }
    SBAR();
    fode(&w, p, pb, yt, k);
    #pragma unroll
    for (int c = 0; c < 4; ++c) { ksum[c] = fmaf(2.0f, k[c], ksum[c]); yt[c] = fmaf(0.5f * h, k[c], y[c]); }
    SBAR();
    fode(&w, p, pb, yt, k);
    #pragma unroll
    for (int c = 0; c < 4; ++c) { ksum[c] = fmaf(2.0f, k[c], ksum[c]); yt[c] = fmaf(h, k[c], y[c]); }
    SBAR();
    fode(&w, p, pb, yt, k);
    #pragma unroll
    for (int c = 0; c < 4; ++c)
      y[c] = fmaf(h * (1.0f / 6.0f), ksum[c] + k[c], y[c]);

    if (!pb) {
      float4 yo; yo.x = y[0]; yo.y = y[1]; yo.z = y[2]; yo.w = y[3];
      ((float4*)out)[(size_t)(t + 1) * B + sys] = yo;
    }
  }
}

extern "C" void kernel_launch(void* const* d_in, const int* in_sizes, int n_in,
                              void* d_out, int out_size, void* d_ws, size_t ws_size,
                              hipStream_t stream) {
  const float* s_grid = (const float*)d_in[0];
  const float* y0     = (const float*)d_in[1];
  const float* W1     = (const float*)d_in[2];
  const float* b1     = (const float*)d_in[3];
  const float* W2     = (const float*)d_in[4];
  const float* b2     = (const float*)d_in[5];
  const float* G1     = (const float*)d_in[6];
  const float* gb1    = (const float*)d_in[7];
  const float* l1g    = (const float*)d_in[8];
  const float* l1b    = (const float*)d_in[9];
  const float* G2     = (const float*)d_in[10];
  const float* gb2    = (const float*)d_in[11];
  const float* l2g    = (const float*)d_in[12];
  const float* l2b    = (const float*)d_in[13];
  const float* G3     = (const float*)d_in[14];
  const float* gb3    = (const float*)d_in[15];

  const int T = in_sizes[0];
  const int B = in_sizes[1] / 4;

  const int threads = 2 * B;  // two lanes per system
  dim3 block(256);
  dim3 grid((threads + 255) / 256);
  hipLaunchKernelGGL(ode_kernel, grid, block, 0, stream,
                     s_grid, y0, W1, b1, W2, b2, G1, gb1, l1g, l1b,
                     G2, gb2, l2g, l2b, G3, gb3, (float*)d_out, T, B);
}